// Round 2
// baseline (237.238 us; speedup 1.0000x reference)
//
#include <hip/hip_runtime.h>

// out = x + 42.0f over 33,554,432 fp32. Memory-bound streaming kernel.
// 268 MB compulsory traffic; floor ~42.6 us @ 6.3 TB/s achievable (m13 ubench).
//
// R1 evidence: harness dur_us=216 includes 2x80us harness fills (512MB @ 6.7TB/s
// each, visible in rocprof); our kernel slice is ~56us = 4.8 TB/s.
// This version matches the known-good 6.29 TB/s float4-copy ubench config:
//   - PLAIN loads/stores (nontemporal hints dropped: both the 6.7 TB/s fills
//     and the 6.29 TB/s copy ubench use plain ops; nt bypasses L2, which is
//     the HBM coalescing point)
//   - grid-stride loop, 2048 blocks (256 CU x 8), per Guideline 11
//   - MLP=4 via stride-separated unroll: 4 independent 16B loads in flight
// n4 = 8,388,608 = 524,288 threads x 16 iters; unroll-4 divides exactly.

typedef float floatx4 __attribute__((ext_vector_type(4)));

__global__ __launch_bounds__(256) void add42_kernel(
    const floatx4* __restrict__ x, floatx4* __restrict__ out, int n4) {
    int stride = gridDim.x * blockDim.x;          // 524,288 threads
    int base = blockIdx.x * blockDim.x + threadIdx.x;

    int i = base;
    // Main loop: 4 independent vectors in flight per iteration.
    for (; i + 3 * stride < n4; i += 4 * stride) {
        floatx4 a = x[i];
        floatx4 b = x[i + stride];
        floatx4 c = x[i + 2 * stride];
        floatx4 d = x[i + 3 * stride];
        a += 42.0f;
        b += 42.0f;
        c += 42.0f;
        d += 42.0f;
        out[i] = a;
        out[i + stride] = b;
        out[i + 2 * stride] = c;
        out[i + 3 * stride] = d;
    }
    // Tail (not taken for the 8192x4096 shape; kept for generality).
    for (; i < n4; i += stride) {
        floatx4 a = x[i];
        a += 42.0f;
        out[i] = a;
    }
}

extern "C" void kernel_launch(void* const* d_in, const int* in_sizes, int n_in,
                              void* d_out, int out_size, void* d_ws, size_t ws_size,
                              hipStream_t stream) {
    const floatx4* x = (const floatx4*)d_in[0];
    floatx4* out = (floatx4*)d_out;
    int n = in_sizes[0];              // 33,554,432 fp32
    int n4 = n >> 2;                  // 8,388,608 16B vectors
    int block = 256;
    int grid = 2048;                  // 256 CUs x 8 blocks; grid-stride covers rest
    add42_kernel<<<grid, block, 0, stream>>>(x, out, n4);
}

// Round 3
// 230.060 us; speedup vs baseline: 1.0312x; 1.0312x over previous
//
#include <hip/hip_runtime.h>

// out = x + 42.0f over 33,554,432 fp32. Memory-bound streaming kernel.
// 268 MB compulsory traffic; floor ~42.6 us @ 6.3 TB/s (full-stream) or
// ~20-25 us if the 134 MB input goes L3-resident (256 MB Infinity Cache).
//
// R2 evidence: plain loads + plain stores showed FETCH = 67 MB = half the
// input — L3 absorbs re-reads, but plain stores write-allocate and evict
// the other half (134+134 > 256 MB). This version:
//   - PLAIN loads: let the input become L3-resident across bench iterations
//   - NONTEMPORAL stores: output stream bypasses allocation -> does not
//     evict the input from L3; HBM carries (mostly) the write stream,
//     which this machine does at 6.7 TB/s (harness fills).
//   - One-shot 8192-block grid, MLP=4 (the R1 config that measured best);
//     exactly one variable changed vs R1's 216.2 us kernel.
// Diagnostic: FETCH_SIZE << 131072 KB confirms L3 residency; ~131072 KB
// means the harness fills thrash L3 between iterations.

typedef float floatx4 __attribute__((ext_vector_type(4)));

__global__ __launch_bounds__(256) void add42_kernel(
    const floatx4* __restrict__ x, floatx4* __restrict__ out, int n4) {
    int base = blockIdx.x * (blockDim.x * 4) + threadIdx.x;
    int i0 = base;
    int i1 = base + blockDim.x;
    int i2 = base + 2 * blockDim.x;
    int i3 = base + 3 * blockDim.x;

    if (i3 < n4) {
        // Fast path: four independent cached loads in flight, then four
        // nontemporal stores.
        floatx4 a = x[i0];
        floatx4 b = x[i1];
        floatx4 c = x[i2];
        floatx4 d = x[i3];
        a += 42.0f;
        b += 42.0f;
        c += 42.0f;
        d += 42.0f;
        __builtin_nontemporal_store(a, &out[i0]);
        __builtin_nontemporal_store(b, &out[i1]);
        __builtin_nontemporal_store(c, &out[i2]);
        __builtin_nontemporal_store(d, &out[i3]);
    } else {
        // Tail (never taken for the 8192x4096 shape: n4 % 1024 == 0).
        for (int i = i0; i < n4; i += blockDim.x) {
            floatx4 a = x[i];
            a += 42.0f;
            __builtin_nontemporal_store(a, &out[i]);
        }
    }
}

extern "C" void kernel_launch(void* const* d_in, const int* in_sizes, int n_in,
                              void* d_out, int out_size, void* d_ws, size_t ws_size,
                              hipStream_t stream) {
    const floatx4* x = (const floatx4*)d_in[0];
    floatx4* out = (floatx4*)d_out;
    int n = in_sizes[0];              // 33,554,432 fp32
    int n4 = n >> 2;                  // 8,388,608 16B vectors
    int block = 256;
    int per_block = block * 4;        // 1024 vectors (16 KB) per block
    int grid = (n4 + per_block - 1) / per_block;  // 8,192 blocks
    add42_kernel<<<grid, block, 0, stream>>>(x, out, n4);
}

// Round 4
// 219.217 us; speedup vs baseline: 1.0822x; 1.0495x over previous
//
#include <hip/hip_runtime.h>

// out = x + 42.0f over 33,554,432 fp32. Memory-bound streaming kernel.
// 268 MB compulsory traffic; kernel floor ~42.6 us @ 6.3 TB/s copy ceiling.
// Harness adds ~160 us of fixed fill cost (2 x 512 MiB poison fills @ 80 us,
// visible in rocprof) inside the timed region -> total floor ~203 us.
//
// Config ladder measured R1-R3 (kernel slice): NT+NT one-shot = 56 us <
// plain+NT one-shot = 70 us < plain+plain grid-stride = 84 us.
//   - NT both directions wins: the 1 GiB/iter harness fills thrash L2/L3
//     between iterations, so caching loads pay allocation cost for zero hits.
//   - One-shot beats grid-stride by ~14 us at fixed cache policy.
// This round, ONE variable vs the R1 winner: block 256 -> 1024 (grid 2048).
// Each block covers a contiguous 64 KB footprint (4x fewer dispatches,
// better HBM channel locality per XCD). MLP=4 unchanged (latency already
// fully hidden: ~128 KB in flight per CU vs ~9 KB needed).

typedef float floatx4 __attribute__((ext_vector_type(4)));

__global__ __launch_bounds__(1024) void add42_kernel(
    const floatx4* __restrict__ x, floatx4* __restrict__ out, int n4) {
    int base = blockIdx.x * (blockDim.x * 4) + threadIdx.x;
    int i0 = base;
    int i1 = base + blockDim.x;
    int i2 = base + 2 * blockDim.x;
    int i3 = base + 3 * blockDim.x;

    if (i3 < n4) {
        // Fast path: four independent NT loads in flight, then four NT stores.
        floatx4 a = __builtin_nontemporal_load(&x[i0]);
        floatx4 b = __builtin_nontemporal_load(&x[i1]);
        floatx4 c = __builtin_nontemporal_load(&x[i2]);
        floatx4 d = __builtin_nontemporal_load(&x[i3]);
        a += 42.0f;
        b += 42.0f;
        c += 42.0f;
        d += 42.0f;
        __builtin_nontemporal_store(a, &out[i0]);
        __builtin_nontemporal_store(b, &out[i1]);
        __builtin_nontemporal_store(c, &out[i2]);
        __builtin_nontemporal_store(d, &out[i3]);
    } else {
        // Tail (never taken for the 8192x4096 shape: n4 % 4096 == 0).
        for (int i = i0; i < n4; i += blockDim.x) {
            floatx4 a = __builtin_nontemporal_load(&x[i]);
            a += 42.0f;
            __builtin_nontemporal_store(a, &out[i]);
        }
    }
}

extern "C" void kernel_launch(void* const* d_in, const int* in_sizes, int n_in,
                              void* d_out, int out_size, void* d_ws, size_t ws_size,
                              hipStream_t stream) {
    const floatx4* x = (const floatx4*)d_in[0];
    floatx4* out = (floatx4*)d_out;
    int n = in_sizes[0];              // 33,554,432 fp32
    int n4 = n >> 2;                  // 8,388,608 16B vectors
    int block = 1024;
    int per_block = block * 4;        // 4096 vectors (64 KB) per block
    int grid = (n4 + per_block - 1) / per_block;  // 2,048 blocks
    add42_kernel<<<grid, block, 0, stream>>>(x, out, n4);
}